// Round 3
// baseline (372.471 us; speedup 1.0000x reference)
//
#include <hip/hip_runtime.h>
#include <hip/hip_bf16.h>

// DotProductNonLocalBlock: B=8, C=512, N=3136 (pad 3200 for xT), E=256.
// No softmax => fully associative. Gram-matrix form:
//   G  = X·X^T                     [bf16 MFMA, K=3136, split-K=2 partials]
//   KV = Wk·G·Wv^T + (Wk s)bv^T + bk(Wv s)^T + N·bk·bv^T   (s = X·1)
//   W2 = wo·KV^T/N ; A2 = W2·wq ; a2 = W2·bq + bo          [small fp32]
//   Out = A2·X + a2 + X            [bf16 MFMA, BK=64, fp32 residual]

typedef __attribute__((ext_vector_type(8))) __bf16 bf16x8;
typedef __attribute__((ext_vector_type(4))) float floatx4;

struct __align__(8) bh4 { __hip_bfloat16 x, y, z, w; };

__device__ __forceinline__ void load_lds16(const void* g, void* l) {
    __builtin_amdgcn_global_load_lds((const __attribute__((address_space(1))) void*)g,
                                     (__attribute__((address_space(3))) void*)l, 16, 0, 0);
}

__global__ void zero_f4(float4* __restrict__ p, int n4) {
    int i = blockIdx.x * 256 + threadIdx.x;
    if (i < n4) p[i] = make_float4(0.f, 0.f, 0.f, 0.f);
}

// x [b][512][3136] fp32 -> xT [b][3200][512] bf16 (pad rows zero)
//                        + xn [b][512][3136] bf16
//                        + s[b][c] += rowsums (atomic)
__global__ __launch_bounds__(256)
void transpose_conv(const float* __restrict__ x, __hip_bfloat16* __restrict__ xT,
                    __hip_bfloat16* __restrict__ xn, float* __restrict__ s)
{
    __shared__ float t[64][65];
    const int b = blockIdx.z;
    const int n0 = blockIdx.x * 64, c0 = blockIdx.y * 64;
    const int tx = threadIdx.x & 15, ty = threadIdx.x >> 4;
    __hip_bfloat16* xo = xT + (long long)b * 3200 * 512;
    const __hip_bfloat16 z = __float2bfloat16(0.f);
    if (n0 >= 3136) {   // pad tile
#pragma unroll
        for (int r = 0; r < 4; ++r) {
            bh4 zz = {z, z, z, z};
            *(bh4*)&xo[(long long)(n0 + ty + 16 * r) * 512 + c0 + tx * 4] = zz;
        }
        return;
    }
    const float* xb = x + (long long)b * 512 * 3136;
    __hip_bfloat16* xnb = xn + (long long)b * 512 * 3136;
    float rs[4];
#pragma unroll
    for (int r = 0; r < 4; ++r) {
        const long long off = (long long)(c0 + ty + 16 * r) * 3136 + n0 + tx * 4;
        float4 v = *(const float4*)&xb[off];
        t[tx * 4 + 0][ty + 16 * r] = v.x;
        t[tx * 4 + 1][ty + 16 * r] = v.y;
        t[tx * 4 + 2][ty + 16 * r] = v.z;
        t[tx * 4 + 3][ty + 16 * r] = v.w;
        bh4 o = {__float2bfloat16(v.x), __float2bfloat16(v.y),
                 __float2bfloat16(v.z), __float2bfloat16(v.w)};
        *(bh4*)&xnb[off] = o;
        rs[r] = v.x + v.y + v.z + v.w;
    }
#pragma unroll
    for (int r = 0; r < 4; ++r) {
#pragma unroll
        for (int m = 1; m < 16; m <<= 1) rs[r] += __shfl_xor(rs[r], m, 16);
    }
    if (tx == 0) {
#pragma unroll
        for (int r = 0; r < 4; ++r)
            atomicAdd(&s[b * 512 + c0 + ty + 16 * r], rs[r]);
    }
    __syncthreads();
#pragma unroll
    for (int r = 0; r < 4; ++r) {
        int nn = ty + 16 * r;
        bh4 o;
        o.x = __float2bfloat16(t[nn][tx * 4 + 0]);
        o.y = __float2bfloat16(t[nn][tx * 4 + 1]);
        o.z = __float2bfloat16(t[nn][tx * 4 + 2]);
        o.w = __float2bfloat16(t[nn][tx * 4 + 3]);
        *(bh4*)&xo[(long long)(n0 + nn) * 512 + c0 + tx * 4] = o;
    }
}

__global__ __launch_bounds__(256)
void cvt_bf16_4(const float4* __restrict__ src, bh4* __restrict__ dst, int n4)
{
    int i = blockIdx.x * 256 + threadIdx.x;
    if (i < n4) {
        float4 v = src[i];
        bh4 o = {__float2bfloat16(v.x), __float2bfloat16(v.y),
                 __float2bfloat16(v.z), __float2bfloat16(v.w)};
        dst[i] = o;
    }
}

// MFMA GEMM, both operands K-contiguous: C[m][n] = sum_k A[m][k]*B[n][k].
// 128x128 tile, template BK (32 or 64), 4 waves (2x2), 16x16x32 MFMAs.
// MODE 2: fp32 out = acc + bias[b][m] + xres[b][m][n], store only n<Nreal.
// MODE 3: fp32 plain store; split-K partials at C + ks*splitStride.
// BK=64 LDS rows are bank-aligned (128B) -> XOR-swizzle 16B k-groups by row&7.
template<int MODE, int BKT>
__global__ __launch_bounds__(256)
void mfma_bt(const __hip_bfloat16* __restrict__ A, long long sA, int lda,
             const __hip_bfloat16* __restrict__ B, long long sB, int ldb,
             float* __restrict__ C, long long sC, int ldc, long long splitStride,
             const float* __restrict__ bias, int sBias,
             const float* __restrict__ xres, long long sX,
             int kLen, int nSplit, int Nreal)
{
    constexpr int CPR = BKT / 8;    // 16B chunks per row
    constexpr int NC  = BKT / 16;   // chunks per thread per matrix (2 or 4)
    constexpr int SWZ = (BKT == 64) ? 7 : 0;
    __shared__ __hip_bfloat16 As[128 * BKT];
    __shared__ __hip_bfloat16 Bs[128 * BKT];
    const int tid = threadIdx.x;
    const int lane = tid & 63;
    const int w = tid >> 6;
    const int wm = (w >> 1) << 6;
    const int wn = (w & 1) << 6;
    const int ln = lane & 15;
    const int hi = lane >> 4;
    const int bz = blockIdx.z;
    const int batch = bz / nSplit;
    const int ks = bz - batch * nSplit;
    const int m0 = blockIdx.y << 7;
    const int n0 = blockIdx.x << 7;
    const long long k0 = (long long)ks * kLen;

    const __hip_bfloat16* gA[NC];
    const __hip_bfloat16* gB[NC];
#pragma unroll
    for (int p = 0; p < NC; ++p) {
        int chunk = tid + 256 * p;
        int row = chunk / CPR;
        int ko = ((chunk % CPR) ^ (row & SWZ)) * 8;
        gA[p] = A + batch * sA + (long long)(m0 + row) * lda + k0 + ko;
        gB[p] = B + batch * sB + (long long)(n0 + row) * ldb + k0 + ko;
    }

    floatx4 acc[4][4] = {};

    const int nK = kLen / BKT;
    for (int kt = 0; kt < nK; ++kt) {
#pragma unroll
        for (int p = 0; p < NC; ++p) {
            load_lds16(gA[p], As + (tid + 256 * p) * 8);
            load_lds16(gB[p], Bs + (tid + 256 * p) * 8);
            gA[p] += BKT; gB[p] += BKT;
        }
        __syncthreads();
#pragma unroll
        for (int kk = 0; kk < BKT / 32; ++kk) {
            bf16x8 af[4], bfr[4];
#pragma unroll
            for (int i = 0; i < 4; ++i) {
                int row = wm + i * 16 + ln;
                af[i] = *(const bf16x8*)(As + row * BKT + (((kk * 4 + hi) ^ (row & SWZ)) << 3));
            }
#pragma unroll
            for (int j = 0; j < 4; ++j) {
                int row = wn + j * 16 + ln;
                bfr[j] = *(const bf16x8*)(Bs + row * BKT + (((kk * 4 + hi) ^ (row & SWZ)) << 3));
            }
#pragma unroll
            for (int i = 0; i < 4; ++i)
#pragma unroll
                for (int j = 0; j < 4; ++j)
                    acc[i][j] = __builtin_amdgcn_mfma_f32_16x16x32_bf16(af[i], bfr[j], acc[i][j], 0, 0, 0);
        }
        __syncthreads();
    }

    // C/D layout: col = lane&15, row = (lane>>4)*4 + r  [m89-verified]
    if (MODE == 3) {
        float* Cb = C + batch * sC + (long long)ks * splitStride;
#pragma unroll
        for (int i = 0; i < 4; ++i) {
            int mb = m0 + wm + i * 16 + hi * 4;
#pragma unroll
            for (int r = 0; r < 4; ++r)
#pragma unroll
                for (int j = 0; j < 4; ++j) {
                    int nl = n0 + wn + j * 16 + ln;
                    Cb[(long long)(mb + r) * ldc + nl] = acc[i][j][r];
                }
        }
    } else {
        float* Cb = C + batch * sC;
        const float* xb = xres + batch * sX;
#pragma unroll
        for (int i = 0; i < 4; ++i) {
            int mb = m0 + wm + i * 16 + hi * 4;
#pragma unroll
            for (int r = 0; r < 4; ++r) {
                float bb = bias[batch * sBias + mb + r];
#pragma unroll
                for (int j = 0; j < 4; ++j) {
                    int nl = n0 + wn + j * 16 + ln;
                    if (nl < Nreal) {
                        long long off = (long long)(mb + r) * ldc + nl;
                        Cb[off] = acc[i][j][r] + bb + xb[off];
                    }
                }
            }
        }
    }
}

// G = Gp[0] + Gp[1]
__global__ __launch_bounds__(256)
void greduce(const float4* __restrict__ Gp, float4* __restrict__ G, int n4)
{
    int i = blockIdx.x * 256 + threadIdx.x;
    if (i < n4) {
        float4 a = Gp[i], b = Gp[i + n4];
        G[i] = make_float4(a.x + b.x, a.y + b.y, a.z + b.z, a.w + b.w);
    }
}

// ks[b][e] = wk[e]·s[b], vs[b][e] = wv[e]·s[b]
__global__ __launch_bounds__(256)
void ksvs_kernel(const float* __restrict__ wk, const float* __restrict__ wv,
                 const float* __restrict__ s, float* __restrict__ ks, float* __restrict__ vs)
{
    int idx = blockIdx.x * 256 + threadIdx.x;   // 0..2047 = b*256 + e
    int b = idx >> 8, e = idx & 255;
    const float4* sv = (const float4*)(s + b * 512);
    const float4* k4 = (const float4*)(wk + (long long)e * 512);
    const float4* v4 = (const float4*)(wv + (long long)e * 512);
    float ak = 0.f, av = 0.f;
#pragma unroll 4
    for (int c = 0; c < 128; ++c) {
        float4 sc = sv[c], kk = k4[c], vv = v4[c];
        ak = fmaf(kk.x, sc.x, ak); ak = fmaf(kk.y, sc.y, ak);
        ak = fmaf(kk.z, sc.z, ak); ak = fmaf(kk.w, sc.w, ak);
        av = fmaf(vv.x, sc.x, av); av = fmaf(vv.y, sc.y, av);
        av = fmaf(vv.z, sc.z, av); av = fmaf(vv.w, sc.w, av);
    }
    ks[idx] = ak; vs[idx] = av;
}

// KV += ks·bv^T + bk·vs^T + N·bk·bv^T
__global__ __launch_bounds__(256)
void fixup_kernel(float* __restrict__ KV, const float* __restrict__ ks,
                  const float* __restrict__ vs, const float* __restrict__ bk,
                  const float* __restrict__ bv)
{
    int idx = blockIdx.x * 256 + threadIdx.x;   // b*65536 + i*256 + j
    int b = idx >> 16, ij = idx & 65535;
    int i = ij >> 8, j = ij & 255;
    KV[idx] += ks[b * 256 + i] * bv[j] + bk[i] * vs[b * 256 + j] + 3136.f * bk[i] * bv[j];
}

// ---- fp32 64x64 GEMM (round-1, verified) for the small steps ----
#define TILE 64
#define BK16 16
#define LDSP (TILE + 4)

template<bool BT>
__global__ __launch_bounds__(256)
void gemm64(const float* __restrict__ A, long long sA, int lda,
            const float* __restrict__ B, long long sB, int ldb,
            float* __restrict__ C, long long sC, int ldc,
            float alpha, int kLen)
{
    __shared__ __align__(16) float As[BK16][LDSP];
    __shared__ __align__(16) float Bs[BK16][LDSP];
    const int tid = threadIdx.x;
    const int tx = tid & 15, ty = tid >> 4;
    const int batch = blockIdx.z;
    const int m0 = blockIdx.y * TILE, n0 = blockIdx.x * TILE;
    const float* Ab = A + (long long)batch * sA;
    const float* Bb = B + (long long)batch * sB;
    float acc[4][4];
#pragma unroll
    for (int i = 0; i < 4; ++i)
#pragma unroll
        for (int j = 0; j < 4; ++j) acc[i][j] = 0.f;
    const int lr = tid >> 2, lk4 = (tid & 3) << 2;
    const int bk_ = tid >> 4, bn4 = (tid & 15) << 2;
    for (int k0 = 0; k0 < kLen; k0 += BK16) {
        float4 av = *(const float4*)&Ab[(long long)(m0 + lr) * lda + k0 + lk4];
        float4 bv;
        if (BT) bv = *(const float4*)&Bb[(long long)(n0 + lr) * ldb + k0 + lk4];
        else    bv = *(const float4*)&Bb[(long long)(k0 + bk_) * ldb + n0 + bn4];
        __syncthreads();
        As[lk4 + 0][lr] = av.x; As[lk4 + 1][lr] = av.y;
        As[lk4 + 2][lr] = av.z; As[lk4 + 3][lr] = av.w;
        if (BT) {
            Bs[lk4 + 0][lr] = bv.x; Bs[lk4 + 1][lr] = bv.y;
            Bs[lk4 + 2][lr] = bv.z; Bs[lk4 + 3][lr] = bv.w;
        } else {
            *(float4*)&Bs[bk_][bn4] = bv;
        }
        __syncthreads();
#pragma unroll
        for (int kk = 0; kk < BK16; ++kk) {
            float4 a4 = *(const float4*)&As[kk][ty << 2];
            float4 b4 = *(const float4*)&Bs[kk][tx << 2];
            const float a[4] = {a4.x, a4.y, a4.z, a4.w};
            const float b[4] = {b4.x, b4.y, b4.z, b4.w};
#pragma unroll
            for (int i = 0; i < 4; ++i)
#pragma unroll
                for (int j = 0; j < 4; ++j)
                    acc[i][j] = fmaf(a[i], b[j], acc[i][j]);
        }
    }
    const int mo = m0 + (ty << 2), no = n0 + (tx << 2);
    float* Cb = C + (long long)batch * sC;
#pragma unroll
    for (int i = 0; i < 4; ++i) {
        float4 v;
        v.x = acc[i][0] * alpha; v.y = acc[i][1] * alpha;
        v.z = acc[i][2] * alpha; v.w = acc[i][3] * alpha;
        *(float4*)&Cb[(long long)(mo + i) * ldc + no] = v;
    }
}

__global__ __launch_bounds__(256)
void a2_kernel(const float* __restrict__ W2, const float* __restrict__ bq,
               const float* __restrict__ bo, float* __restrict__ a2)
{
    int idx = blockIdx.x * 256 + threadIdx.x;   // b*512 + c
    int c = idx & 511;
    const float4* row = (const float4*)(W2 + (long long)idx * 256);
    const float4* q4 = (const float4*)bq;
    float s = 0.f;
#pragma unroll 4
    for (int e = 0; e < 64; ++e) {
        float4 w = row[e], b = q4[e];
        s = fmaf(w.x, b.x, s); s = fmaf(w.y, b.y, s);
        s = fmaf(w.z, b.z, s); s = fmaf(w.w, b.w, s);
    }
    a2[idx] = s + bo[c];
}

extern "C" void kernel_launch(void* const* d_in, const int* in_sizes, int n_in,
                              void* d_out, int out_size, void* d_ws, size_t ws_size,
                              hipStream_t stream)
{
    const float* x  = (const float*)d_in[0];
    const float* wq = (const float*)d_in[1];
    const float* bq = (const float*)d_in[2];
    const float* wk = (const float*)d_in[3];
    const float* bk = (const float*)d_in[4];
    const float* wv = (const float*)d_in[5];
    const float* bv = (const float*)d_in[6];
    const float* wo = (const float*)d_in[7];
    const float* bo = (const float*)d_in[8];
    float* out = (float*)d_out;

    const int C = 512, E = 256, N = 3136;
    const long long xs = (long long)C * N;   // 1,605,632

    // d_out scratch (51,380,224 B), liveness-overlapped, all dead before final write:
    char* ob = (char*)d_out;
    __hip_bfloat16* xn = (__hip_bfloat16*)ob;                  // @0        25,690,112  (dead after G)
    float* Gp  = (float*)(ob + 25690112);                      // 2x8x512x512 = 16,777,216 (dead after reduce)
    float* G   = (float*)(ob + 42467328);                      //  8,388,608  (dead after T1)
    float* T1  = (float*)(ob + 0);                             //  4,194,304  over dead xn (dead after T2)
    float* KV  = (float*)(ob + 4194304);                       //  2,097,152
    float* W2  = (float*)(ob + 6291456);                       //  4,194,304
    float* A2  = (float*)(ob + 10485760);                      //  8,388,608

    // ws (~30.5 MB, within round-2-proven budget)
    char* wsb = (char*)d_ws;
    __hip_bfloat16* xT  = (__hip_bfloat16*)wsb;                // 26,214,400
    __hip_bfloat16* A2b = (__hip_bfloat16*)(wsb + 26214400);   //  4,194,304
    float* sv  = (float*)(wsb + 30408704);                     //     16,384
    float* ksv = (float*)(wsb + 30425088);                     //      8,192
    float* vsv = (float*)(wsb + 30433280);                     //      8,192
    float* a2v = (float*)(wsb + 30441472);                     //     16,384

    // 0) zero s (atomic accumulator)
    zero_f4<<<4, 256, 0, stream>>>((float4*)sv, 1024);

    // 1) xT (bf16, padded-transposed) + xn (bf16) + s (rowsums)
    transpose_conv<<<dim3(50, 8, 8), 256, 0, stream>>>(x, xT, xn, sv);

    // 2) Gp = xn·xn^T split-K=2 (K=1568 each, 49 iters, 256 blocks = 1/CU)
    mfma_bt<3, 32><<<dim3(4, 4, 16), 256, 0, stream>>>(
        xn, xs, N, xn, xs, N, Gp, (long long)C * C, C, 8LL * C * C,
        nullptr, 0, nullptr, 0, 1568, 2, C);

    // 3) G = Gp[0] + Gp[1]
    greduce<<<2048, 256, 0, stream>>>((const float4*)Gp, (float4*)G, 524288);

    // 4) ks = Wk·s, vs = Wv·s
    ksvs_kernel<<<8, 256, 0, stream>>>(wk, wv, sv, ksv, vsv);

    // 5) T1 = G·Wv^T   (M=512, N=256, K=512)
    gemm64<true><<<dim3(4, 8, 8), 256, 0, stream>>>(
        G, (long long)C * C, C, wv, 0, C, T1, (long long)C * E, E, 1.f, C);

    // 6) KV = Wk·T1    (M=256, N=256, K=512)
    gemm64<false><<<dim3(4, 4, 8), 256, 0, stream>>>(
        wk, 0, C, T1, (long long)C * E, E, KV, (long long)E * E, E, 1.f, C);

    // 7) KV += rank-1 bias terms
    fixup_kernel<<<2048, 256, 0, stream>>>(KV, ksv, vsv, bk, bv);

    // 8) W2 = wo·KV^T / N   (M=512, N=256, K=256)
    gemm64<true><<<dim3(4, 8, 8), 256, 0, stream>>>(
        wo, 0, E, KV, (long long)E * E, E, W2, (long long)C * E, E, 1.f / (float)N, E);

    // 9) A2 = W2·wq   (M=512, N=512, K=256)
    gemm64<false><<<dim3(8, 8, 8), 256, 0, stream>>>(
        W2, (long long)C * E, E, wq, 0, C, A2, (long long)C * C, C, 1.f, E);

    // 10) a2 = W2·bq + bo
    a2_kernel<<<16, 256, 0, stream>>>(W2, bq, bo, a2v);

    // 11) A2 -> bf16
    cvt_bf16_4<<<2048, 256, 0, stream>>>((const float4*)A2, (bh4*)A2b, 524288);

    // 12) out = A2b·X + a2 + x   (M=512, N=3136, K=512, BK=64)
    mfma_bt<2, 64><<<dim3(25, 4, 8), 256, 0, stream>>>(
        A2b, (long long)C * C, C, xT, 3200LL * C, C,
        out, xs, N, 0, a2v, C, x, xs, 512, 1, N);
}